// Round 5
// baseline (2600.880 us; speedup 1.0000x reference)
//
#include <hip/hip_runtime.h>

// ---------------------------------------------------------------------------
// SpatioTemporalTransformerXL forward on gfx950.
//  - residual stream h stays fp32 in d_out, updated in place
//  - LN kernels emit bf16 x; all GEMMs are bf16 MFMA (16x16x32), fp32 acc
//  - GEMM: 256x256 tile, BK=64, 8 waves (2Mx4N), 2-buffer LDS (128KB),
//    wave-local software-pipelined ds_reads with COUNTED lgkmcnt (reads for
//    quadrant q+1 issued before MFMA of quadrant q; next tile's a0/b0 burst
//    issued right after the barrier, hidden under Q3), one barrier per
//    K-tile, stages all target the opposite buffer, setprio around MFMA,
//    XOR granule swizzle (conflict-free), XCD-aware block swizzle.
// ---------------------------------------------------------------------------

#define AS1 __attribute__((address_space(1)))
#define AS3 __attribute__((address_space(3)))

using bf16x8 = __attribute__((ext_vector_type(8))) short;   // 8 bf16 = 4 VGPRs
using f32x4  = __attribute__((ext_vector_type(4))) float;

__device__ __forceinline__ f32x4 mfma_bf16(bf16x8 a, bf16x8 b, f32x4 c) {
  return __builtin_amdgcn_mfma_f32_16x16x32_bf16(a, b, c, 0, 0, 0);
}

__device__ __forceinline__ void async16(const void* g, void* l) {
  __builtin_amdgcn_global_load_lds((const AS1 void*)g, (AS3 void*)l, 16, 0, 0);
}

// fp32 -> bf16 RNE
__device__ __forceinline__ short f2bs(float f) {
  union { float f; unsigned u; } x; x.f = f;
  unsigned r = x.u + 0x7fffu + ((x.u >> 16) & 1u);
  return (short)(r >> 16);
}

__device__ __forceinline__ f32x4 fzero() {
  f32x4 v; v[0] = 0.f; v[1] = 0.f; v[2] = 0.f; v[3] = 0.f; return v;
}

__device__ __forceinline__ float quad16_max(float v) {
  v = fmaxf(v, __shfl_xor(v, 1));
  v = fmaxf(v, __shfl_xor(v, 2));
  v = fmaxf(v, __shfl_xor(v, 4));
  v = fmaxf(v, __shfl_xor(v, 8));
  return v;
}
__device__ __forceinline__ float quad16_sum(float v) {
  v += __shfl_xor(v, 1); v += __shfl_xor(v, 2);
  v += __shfl_xor(v, 4); v += __shfl_xor(v, 8);
  return v;
}

#define LGKM(n) asm volatile("s_waitcnt lgkmcnt(" #n ")" ::: "memory"); \
                __builtin_amdgcn_sched_barrier(0)
#define SCHED_FENCE() __builtin_amdgcn_sched_barrier(0)

// ---------------------------------------------------------------------------
// GEMM: C[M,N] = A[M,K](bf16) * BT[N,K]^T(bf16)  + epilogue
// MODE 0: outB = bf16(acc)                       (QKV projections)
// MODE 1: outF = acc + bias[col] + resid         (output proj / FFN2, fp32)
// MODE 2: outB = bf16(gelu_tanh(acc + bias))     (FFN1)
//
// Tile 256x256, BK=64, 8 waves = 2M x 4N, per-wave output 128x64
// (acc[8][4] 16x16 fragments).  LDS: 2 buffers x (A[256][64] | B[256][64]).
// B region lives at tile-base + 16384 shorts; RD_B* add that internally
// (round-4 bug: two call sites passed the A base -> garbage B operands).
// Rows are 128B = 8 granules of 16B; granule g of row r stored at g ^ (r&7)
// (conflict-free ds_read_b128); global_load_lds inverts the swizzle in the
// per-lane global k-offset (LDS dest stays lane-linear).
//
// Per K-tile u (read buffer u&1), single pipelined stream per wave
// (quadrants Q0=a0b0, Q1=a0b1, Q2=a1b0, Q3=a1b1; outstanding-lgkm ledger
// in brackets; stages all target buffer ^1):
//   s1 : read b1 (4)              [12 -> 16]
//   s2 : lgkm(4)   -> a0,b0 ready (issued after last tile's barrier)
//   s3 : Q0
//   s4 : STAGE A0(u+1), A1(u+1)
//   s5 : read a1 (8)              [4 -> 12]
//   s6 : lgkm(8)   -> b1 ready
//   s7 : Q1
//   s8 : STAGE B0(u+1), B1(u+1)
//   s9 : lgkm(0)   -> a1 ready
//   s10: Q2
//   s11: vmcnt(0)  (stages issued 1-2 MFMA phases earlier -> mostly drained)
//   s12: s_barrier (publishes buffer u+1)
//   s13: read next a0 (8), b0 (4) from buffer u+1   [0 -> 12]
//   s14: Q3        (covers the s13 read burst)
// Liveness: a0,b0 dead after Q1/Q2 -> safely overwritten by s13.
// Skew safety: in window (bar(u), bar(u+1)) reads hit buffer u+1 only
// (s13 of u; s1,s5 of u+1), stages hit buffer u only (s4,s8 of u+1); each
// wave's lgkm(0) at s9 precedes its barrier, vmcnt(0) precedes publish.
// ---------------------------------------------------------------------------
template<int MODE>
__global__ __launch_bounds__(512, 2) void gemm256(
    const short* __restrict__ A, const short* __restrict__ BT,
    const float* __restrict__ bias, const float* __restrict__ resid,
    float* __restrict__ outF, short* __restrict__ outB,
    int M, int N, int K, int nx)
{
  __shared__ __align__(16) short lds[65536];   // 128KB: 2 x (A 32KB | B 32KB)
  (void)M;
  const int tid  = threadIdx.x;
  const int lane = tid & 63, wave = tid >> 6;
  const int quad = lane >> 4, l16 = lane & 15;
  const int wm = wave >> 2, wn = wave & 3;     // 2 x 4 wave grid, 128x64 each

  // XCD-aware swizzle: 8 consecutive blocks (one per XCD) share a B panel;
  // per XCD, nx consecutive blocks share one A row-panel (L2-resident).
  const unsigned flat = blockIdx.x;
  const unsigned su = flat >> 3;
  const unsigned nxu = (unsigned)nx;
  const long bm0 = (long)((flat & 7u) + 8u * (su / nxu)) * 256;
  const long bn0 = (long)(su % nxu) * 256;

  // ---- staging geometry: 1 gload instr = 512thr x 16B = 64 rows x 128B ----
  const int trow = tid >> 3;                       // row within 8KB chunk
  const int tg   = ((tid & 7) ^ (trow & 7)) * 8;   // swizzle-inverted granule
  const short* As = A  + (bm0 + trow) * (long)K + tg;
  const short* Bs = BT + (bn0 + trow) * (long)K + tg;

  auto STAGE = [&](int tile, int isB, int half) {
    const short* sp = (isB ? Bs : As) + (long)half * 128 * K + (long)tile * 64;
    char* db = (char*)lds + (tile & 1) * 65536 + isB * 32768 + half * 16384
             + (tid << 4);
    async16(sp, db);
    async16(sp + ((long)K << 6), db + 8192);
  };

  // ---- fragment ds_read bases (shorts) ----
  const int swg   = (quad ^ (l16 & 7)) * 8;        // kk=0 swizzled granule off
  const int arow0 = wm * 128 + l16;
  const int brow0 = wn * 64 + l16;

  f32x4 acc[8][4];
#pragma unroll
  for (int i = 0; i < 8; ++i)
#pragma unroll
    for (int j = 0; j < 4; ++j) acc[i][j] = fzero();

  const int nt = K >> 6;                           // K/64: 12 or 48

  bf16x8 a0[4][2], a1[4][2], b0[2][2], b1[2][2];

// base = tile base (A region); B region at base + 16384 shorts
#define RD_A0(base)                                                           \
  _Pragma("unroll") for (int i = 0; i < 4; ++i) {                             \
    a0[i][0] = *(const bf16x8*)((base) + (arow0 + i * 16) * 64 + swg);        \
    a0[i][1] = *(const bf16x8*)((base) + (arow0 + i * 16) * 64 + (swg ^ 32)); \
  }
#define RD_A1(base)                                                           \
  _Pragma("unroll") for (int i = 0; i < 4; ++i) {                             \
    a1[i][0] = *(const bf16x8*)((base) + (arow0 + 64 + i * 16) * 64 + swg);   \
    a1[i][1] = *(const bf16x8*)((base) + (arow0 + 64 + i * 16) * 64 + (swg ^ 32)); \
  }
#define RD_B0(base)                                                           \
  _Pragma("unroll") for (int j = 0; j < 2; ++j) {                             \
    b0[j][0] = *(const bf16x8*)((base) + 16384 + (brow0 + j * 16) * 64 + swg);\
    b0[j][1] = *(const bf16x8*)((base) + 16384 + (brow0 + j * 16) * 64 + (swg ^ 32)); \
  }
#define RD_B1(base)                                                           \
  _Pragma("unroll") for (int j = 0; j < 2; ++j) {                             \
    b1[j][0] = *(const bf16x8*)((base) + 16384 + (brow0 + 32 + j * 16) * 64 + swg); \
    b1[j][1] = *(const bf16x8*)((base) + 16384 + (brow0 + 32 + j * 16) * 64 + (swg ^ 32)); \
  }
#define QUAD(AF, BF, IO, JO)                                                  \
  __builtin_amdgcn_s_setprio(1);                                              \
  _Pragma("unroll") for (int kk = 0; kk < 2; ++kk)                            \
    _Pragma("unroll") for (int i = 0; i < 4; ++i)                             \
      _Pragma("unroll") for (int j = 0; j < 2; ++j)                           \
        acc[(IO) + i][(JO) + j] = mfma_bf16(AF[i][kk], BF[j][kk], acc[(IO) + i][(JO) + j]); \
  __builtin_amdgcn_s_setprio(0)

  // prologue: stage tile0, publish, issue a0/b0 burst (12 outstanding)
  STAGE(0, 0, 0); STAGE(0, 0, 1); STAGE(0, 1, 0); STAGE(0, 1, 1);
  asm volatile("s_waitcnt vmcnt(0)" ::: "memory");
  __builtin_amdgcn_s_barrier();
  SCHED_FENCE();
  RD_A0(lds); RD_B0(lds);
  SCHED_FENCE();

  for (int u = 0; u < nt; ++u) {
    const short* buf  = lds + (u & 1) * 32768;        // tile base (A region)
    const short* nbuf = lds + ((u + 1) & 1) * 32768;
    const bool pf = (u + 1 < nt);

    RD_B1(buf);                            // s1   [12 -> 16]
    LGKM(4);                               // s2   a0,b0 ready
    QUAD(a0, b0, 0, 0);                    // s3   Q0
    if (pf) { STAGE(u + 1, 0, 0); STAGE(u + 1, 0, 1); }   // s4
    RD_A1(buf);                            // s5   [4 -> 12]
    SCHED_FENCE();
    LGKM(8);                               // s6   b1 ready
    QUAD(a0, b1, 0, 2);                    // s7   Q1
    if (pf) { STAGE(u + 1, 1, 0); STAGE(u + 1, 1, 1); }   // s8
    LGKM(0);                               // s9   a1 ready
    QUAD(a1, b0, 4, 0);                    // s10  Q2
    if (pf) {
      asm volatile("s_waitcnt vmcnt(0)" ::: "memory");    // s11
      __builtin_amdgcn_s_barrier();                       // s12
      SCHED_FENCE();
      RD_A0(nbuf); RD_B0(nbuf);            // s13  [0 -> 12]
      SCHED_FENCE();
    }
    QUAD(a1, b1, 4, 2);                    // s14  Q3 (covers s13 burst)
  }

#undef RD_A0
#undef RD_A1
#undef RD_B0
#undef RD_B1
#undef QUAD

  // ---- epilogue (C/D layout: col=l16, row=quad*4+r) ----
  const long rowbase = bm0 + wm * 128 + quad * 4;
  const long colbase = bn0 + wn * 64 + l16;
#pragma unroll
  for (int i = 0; i < 8; ++i)
#pragma unroll
    for (int j = 0; j < 4; ++j) {
      const long gc = colbase + j * 16;
#pragma unroll
      for (int r = 0; r < 4; ++r) {
        const long gr = rowbase + i * 16 + r;
        const size_t idx = (size_t)gr * N + gc;
        float v = acc[i][j][r];
        if (MODE == 0) {
          outB[idx] = f2bs(v);
        } else if (MODE == 1) {
          outF[idx] = v + bias[gc] + resid[idx];
        } else {
          float tt = v + bias[gc];
          float z = 0.7978845608f * (tt + 0.044715f * tt * tt * tt);
          float g = __fdividef(tt, 1.f + __expf(-2.f * z));
          outB[idx] = f2bs(g);
        }
      }
    }
}

// ---------------------------------------------------------------------------
// LayerNorm: h fp32 [16384,768] -> bf16 x, one block per row, 256 threads.
// ---------------------------------------------------------------------------
__global__ __launch_bounds__(256) void ln_kernel(
    const float* __restrict__ h, const float* __restrict__ sc,
    const float* __restrict__ bi, short* __restrict__ out)
{
  const int row = blockIdx.x, tid = threadIdx.x;
  const float* hr = h + (long)row * 768;
  float x0 = hr[tid], x1 = hr[tid + 256], x2 = hr[tid + 512];
  __shared__ float red[4];
  float s = x0 + x1 + x2;
#pragma unroll
  for (int m = 32; m >= 1; m >>= 1) s += __shfl_xor(s, m);
  if ((tid & 63) == 0) red[tid >> 6] = s;
  __syncthreads();
  float mean = (red[0] + red[1] + red[2] + red[3]) * (1.f / 768.f);
  float d0 = x0 - mean, d1 = x1 - mean, d2 = x2 - mean;
  float q = d0 * d0 + d1 * d1 + d2 * d2;
#pragma unroll
  for (int m = 32; m >= 1; m >>= 1) q += __shfl_xor(q, m);
  __syncthreads();
  if ((tid & 63) == 0) red[tid >> 6] = q;
  __syncthreads();
  float var = (red[0] + red[1] + red[2] + red[3]) * (1.f / 768.f);
  float inv = rsqrtf(var + 1e-5f);
  long o = (long)row * 768;
  out[o + tid]       = f2bs(d0 * inv * sc[tid]       + bi[tid]);
  out[o + tid + 256] = f2bs(d1 * inv * sc[tid + 256] + bi[tid + 256]);
  out[o + tid + 512] = f2bs(d2 * inv * sc[tid + 512] + bi[tid + 512]);
}

// ---------------------------------------------------------------------------
// Weight transpose + bf16 cast: in fp32 [Kd][Nd] -> out bf16 [Nd][Kd]
// z = layer index (batched over gridDim.z)
// ---------------------------------------------------------------------------
__global__ __launch_bounds__(256) void transpose_w(
    const float* __restrict__ in, short* __restrict__ out, int Kd, int Nd,
    long inStride, long outStride)
{
  __shared__ float t[32][33];
  const int z = blockIdx.z;
  in  += (long)z * inStride;
  out += (long)z * outStride;
  const int n0 = blockIdx.x * 32, k0 = blockIdx.y * 32;
  const int r = threadIdx.x >> 5, c = threadIdx.x & 31;
#pragma unroll
  for (int rr = 0; rr < 4; ++rr)
    t[r + rr * 8][c] = in[(long)(k0 + r + rr * 8) * Nd + n0 + c];
  __syncthreads();
#pragma unroll
  for (int rr = 0; rr < 4; ++rr)
    out[(long)(n0 + r + rr * 8) * Kd + k0 + c] = f2bs(t[c][r + rr * 8]);
}

// ---------------------------------------------------------------------------
// Space attention: softmax over L=256. Grid (qtile=4, head=12, b*t=64),
// 256 threads = 4 waves; each wave owns 16 q-rows. qkv row stride 2304:
// cols [0,768) Q, [768,1536) K, [1536,2304) V, packed h*64+d.
// ---------------------------------------------------------------------------
__global__ __launch_bounds__(256) void attn_space(
    const short* __restrict__ qkv, short* __restrict__ ao)
{
  __shared__ __align__(16) short VT[64 * 256];      // VT[d][l]
  __shared__ __align__(16) short P[4][16 * 256];    // per-wave P[q][l]
  const int qt = blockIdx.x, hh = blockIdx.y, bt = blockIdx.z;
  const long tok0 = (long)bt * 256;
  const int tid = threadIdx.x, wave = tid >> 6, lane = tid & 63;
  const int quad = lane >> 4, l16 = lane & 15;

  // stage V^T
#pragma unroll
  for (int it = 0; it < 8; ++it) {
    int chunk = it * 256 + tid;
    int vl = chunk >> 3, d8 = (chunk & 7) * 8;
    bf16x8 v = *(const bf16x8*)(qkv + (tok0 + vl) * 2304 + 1536 + hh * 64 + d8);
#pragma unroll
    for (int e = 0; e < 8; ++e) VT[(d8 + e) * 256 + vl] = v[e];
  }

  const int qr = qt * 64 + wave * 16;
  bf16x8 qf[2];
#pragma unroll
  for (int kk = 0; kk < 2; ++kk)
    qf[kk] = *(const bf16x8*)(qkv + (tok0 + qr + l16) * 2304 + hh * 64 + kk * 32 + quad * 8);

  f32x4 S[16];
#pragma unroll
  for (int j = 0; j < 16; ++j) S[j] = fzero();
#pragma unroll
  for (int j = 0; j < 16; ++j)
#pragma unroll
    for (int kk = 0; kk < 2; ++kk) {
      bf16x8 kf = *(const bf16x8*)(qkv + (tok0 + j * 16 + l16) * 2304 + 768 + hh * 64 + kk * 32 + quad * 8);
      S[j] = mfma_bf16(qf[kk], kf, S[j]);
    }

  // softmax rows quad*4+r  (C/D layout: col=l16, row=quad*4+reg)
#pragma unroll
  for (int r = 0; r < 4; ++r) {
    float m = -1e30f;
#pragma unroll
    for (int j = 0; j < 16; ++j) m = fmaxf(m, S[j][r]);
    m = quad16_max(m);
    float sum = 0.f;
#pragma unroll
    for (int j = 0; j < 16; ++j) {
      float e = __expf((S[j][r] - m) * 0.125f);
      S[j][r] = e; sum += e;
    }
    sum = quad16_sum(sum);
    float inv = 1.f / sum;
#pragma unroll
    for (int j = 0; j < 16; ++j)
      P[wave][(quad * 4 + r) * 256 + j * 16 + l16] = f2bs(S[j][r] * inv);
  }
  __syncthreads();

  // O = P (A-layout from LDS) * V (B-layout from VT)
  f32x4 O[4];
#pragma unroll
  for (int jn = 0; jn < 4; ++jn) O[jn] = fzero();
  for (int kk = 0; kk < 8; ++kk) {
    bf16x8 pf = *(const bf16x8*)&P[wave][l16 * 256 + kk * 32 + quad * 8];
#pragma unroll
    for (int jn = 0; jn < 4; ++jn) {
      bf16x8 vf = *(const bf16x8*)&VT[(jn * 16 + l16) * 256 + kk * 32 + quad * 8];
      O[jn] = mfma_bf16(pf, vf, O[jn]);
    }
  }
#pragma unroll
  for (int jn = 0; jn < 4; ++jn)
#pragma unroll
    for (int r = 0; r < 4; ++r) {
      int row = qr + quad * 4 + r;
      ao[(tok0 + row) * 768 + hh * 64 + jn * 16 + l16] = f2bs(O[jn][r]);
    }
}

// ---------------------------------------------------------------------------
// Time attention: softmax over T=32. Grid (l=256, head=12, b=2), 1 wave.
// token(t) = (b*32+t)*256 + l
// ---------------------------------------------------------------------------
__global__ __launch_bounds__(64) void attn_time(
    const short* __restrict__ qkv, short* __restrict__ ao)
{
  __shared__ __align__(16) short VT[64 * 32];   // VT[d][t]
  __shared__ __align__(16) short P[32 * 32];    // P[t_q][t_k]
  const int ll = blockIdx.x, hh = blockIdx.y, b = blockIdx.z;
  const int lane = threadIdx.x;
  const int quad = lane >> 4, l16 = lane & 15;
#define TOK(t) (((long)(b * 32 + (t))) * 256 + ll)

#pragma unroll
  for (int it = 0; it < 4; ++it) {
    int chunk = it * 64 + lane;
    int t = chunk >> 3, d8 = (chunk & 7) * 8;
    bf16x8 v = *(const bf16x8*)(qkv + TOK(t) * 2304 + 1536 + hh * 64 + d8);
#pragma unroll
    for (int e = 0; e < 8; ++e) VT[(d8 + e) * 32 + t] = v[e];
  }

  bf16x8 qf[2][2];
#pragma unroll
  for (int mi = 0; mi < 2; ++mi)
#pragma unroll
    for (int kk = 0; kk < 2; ++kk)
      qf[mi][kk] = *(const bf16x8*)(qkv + TOK(mi * 16 + l16) * 2304 + hh * 64 + kk * 32 + quad * 8);

  f32x4 S[2][2];
#pragma unroll
  for (int mi = 0; mi < 2; ++mi) { S[mi][0] = fzero(); S[mi][1] = fzero(); }
#pragma unroll
  for (int nj = 0; nj < 2; ++nj)
#pragma unroll
    for (int kk = 0; kk < 2; ++kk) {
      bf16x8 kf = *(const bf16x8*)(qkv + TOK(nj * 16 + l16) * 2304 + 768 + hh * 64 + kk * 32 + quad * 8);
#pragma unroll
      for (int mi = 0; mi < 2; ++mi)
        S[mi][nj] = mfma_bf16(qf[mi][kk], kf, S[mi][nj]);
    }

#pragma unroll
  for (int mi = 0; mi < 2; ++mi)
#pragma unroll
    for (int r = 0; r < 4; ++r) {
      float m = fmaxf(S[mi][0][r], S[mi][1][r]);
      m = quad16_max(m);
      float e0 = __expf((S[mi][0][r] - m) * 0.125f);
      float e1 = __expf((S[mi][1][r] - m) * 0.125f);
      float sum = quad16_sum(e0 + e1);
      float inv = 1.f / sum;
      P[(mi * 16 + quad * 4 + r) * 32 + l16]      = f2bs(e0 * inv);
      P[(mi * 16 + quad * 4 + r) * 32 + 16 + l16] = f2bs(e1 * inv);
    }
  __syncthreads();

  f32x4 O[2][4];
#pragma unroll
  for (int mi = 0; mi < 2; ++mi)
#pragma unroll
    for (int jn = 0; jn < 4; ++jn) O[mi][jn] = fzero();
#pragma unroll
  for (int mi = 0; mi < 2; ++mi) {
    bf16x8 pf = *(const bf16x8*)&P[(mi * 16 + l16) * 32 + quad * 8];
#pragma unroll
    for (int jn = 0; jn < 4; ++jn) {
      bf16x8 vf = *(const bf16x8*)&VT[(jn * 16 + l16) * 32 + quad * 8];
      O[mi][jn] = mfma_bf16(pf, vf, O[mi][jn]);
    }
  }
#pragma unroll
  for (int mi = 0; mi < 2; ++mi)
#pragma unroll
    for (int jn = 0; jn < 4; ++jn)
#pragma unroll
      for (int r = 0; r < 4; ++r) {
        int t = mi * 16 + quad * 4 + r;
        ao[TOK(t) * 768 + hh * 64 + jn * 16 + l16] = f2bs(O[mi][jn][r]);
      }
#undef TOK
}

// ---------------------------------------------------------------------------
extern "C" void kernel_launch(void* const* d_in, const int* in_sizes, int n_in,
                              void* d_out, int out_size, void* d_ws, size_t ws_size,
                              hipStream_t stream)
{
  const float* emb     = (const float*)d_in[0];
  const float* Wq_t    = (const float*)d_in[1];
  const float* Wk_t    = (const float*)d_in[2];
  const float* Wv_t    = (const float*)d_in[3];
  const float* Wo_t    = (const float*)d_in[4];
  const float* bo_t    = (const float*)d_in[5];
  const float* Wq_s    = (const float*)d_in[6];
  const float* Wk_s    = (const float*)d_in[7];
  const float* Wv_s    = (const float*)d_in[8];
  const float* Wo_s    = (const float*)d_in[9];
  const float* bo_s    = (const float*)d_in[10];
  const float* ln_t_sc = (const float*)d_in[11];
  const float* ln_t_bi = (const float*)d_in[12];
  const float* ln_s_sc = (const float*)d_in[13];
  const float* ln_s_bi = (const float*)d_in[14];
  const float* ln2_sc  = (const float*)d_in[15];
  const float* ln2_bi  = (const float*)d_in[16];
  const float* W1      = (const float*)d_in[17];
  const float* b1      = (const float*)d_in[18];
  const float* W2      = (const float*)d_in[19];
  const float* b2      = (const float*)d_in[20];

  const long M = 16384, D = 768, QN = 2304, F = 3072;
  char* ws = (char*)d_ws;
  size_t off = 0;
  auto alloc = [&](size_t b) { char* p = ws + off; off += (b + 255) & ~(size_t)255; return p; };
  short* qkvT_t = (short*)alloc((size_t)4 * QN * D * 2);   // 14.2 MB
  short* qkvT_s = (short*)alloc((size_t)4 * QN * D * 2);   // 14.2 MB
  short* woT_t  = (short*)alloc((size_t)4 * D * D * 2);    //  4.7 MB
  short* woT_s  = (short*)alloc((size_t)4 * D * D * 2);    //  4.7 MB
  short* w1T    = (short*)alloc((size_t)4 * F * D * 2);    // 18.9 MB
  short* w2T    = (short*)alloc((size_t)4 * D * F * 2);    // 18.9 MB
  short* xb     = (short*)alloc((size_t)M * D * 2);        // 25.2 MB
  short* aob    = (short*)alloc((size_t)M * D * 2);        // 25.2 MB
  short* big    = (short*)alloc((size_t)M * F * 2);        // 100.7 MB (qkv & ffn1)
  float* h = (float*)d_out;

  hipMemcpyAsync(h, emb, (size_t)M * D * 4, hipMemcpyDeviceToDevice, stream);

  // ---- weight prep: fp32 [K][N] -> bf16 [N][K], all 4 layers per launch ------
  transpose_w<<<dim3(24, 24, 4), 256, 0, stream>>>(Wq_t, qkvT_t,             768, 768,  D * D, QN * D);
  transpose_w<<<dim3(24, 24, 4), 256, 0, stream>>>(Wk_t, qkvT_t + D * D,     768, 768,  D * D, QN * D);
  transpose_w<<<dim3(24, 24, 4), 256, 0, stream>>>(Wv_t, qkvT_t + 2 * D * D, 768, 768,  D * D, QN * D);
  transpose_w<<<dim3(24, 24, 4), 256, 0, stream>>>(Wq_s, qkvT_s,             768, 768,  D * D, QN * D);
  transpose_w<<<dim3(24, 24, 4), 256, 0, stream>>>(Wk_s, qkvT_s + D * D,     768, 768,  D * D, QN * D);
  transpose_w<<<dim3(24, 24, 4), 256, 0, stream>>>(Wv_s, qkvT_s + 2 * D * D, 768, 768,  D * D, QN * D);
  transpose_w<<<dim3(24, 24, 4), 256, 0, stream>>>(Wo_t, woT_t,              768, 768,  D * D, D * D);
  transpose_w<<<dim3(24, 24, 4), 256, 0, stream>>>(Wo_s, woT_s,              768, 768,  D * D, D * D);
  transpose_w<<<dim3(96, 24, 4), 256, 0, stream>>>(W1,   w1T,                768, 3072, D * F, F * D);
  transpose_w<<<dim3(24, 96, 4), 256, 0, stream>>>(W2,   w2T,                3072, 768, F * D, D * F);

  // ---- layers ---------------------------------------------------------------
  for (int l = 0; l < 4; ++l) {
    // time attention block
    ln_kernel<<<16384, 256, 0, stream>>>(h, ln_t_sc + l * 768, ln_t_bi + l * 768, xb);
    gemm256<0><<<9 * 64, 512, 0, stream>>>(xb, qkvT_t + (long)l * QN * D,
        nullptr, nullptr, nullptr, big, 16384, 2304, 768, 9);
    attn_time<<<dim3(256, 12, 2), 64, 0, stream>>>(big, aob);
    gemm256<1><<<3 * 64, 512, 0, stream>>>(aob, woT_t + (long)l * D * D,
        bo_t + l * 768, h, h, nullptr, 16384, 768, 768, 3);
    // space attention block
    ln_kernel<<<16384, 256, 0, stream>>>(h, ln_s_sc + l * 768, ln_s_bi + l * 768, xb);
    gemm256<0><<<9 * 64, 512, 0, stream>>>(xb, qkvT_s + (long)l * QN * D,
        nullptr, nullptr, nullptr, big, 16384, 2304, 768, 9);
    attn_space<<<dim3(4, 12, 64), 256, 0, stream>>>(big, aob);
    gemm256<1><<<3 * 64, 512, 0, stream>>>(aob, woT_s + (long)l * D * D,
        bo_s + l * 768, h, h, nullptr, 16384, 768, 768, 3);
    // FFN block
    ln_kernel<<<16384, 256, 0, stream>>>(h, ln2_sc + l * 768, ln2_bi + l * 768, xb);
    gemm256<2><<<12 * 64, 512, 0, stream>>>(xb, w1T + (long)l * F * D,
        b1 + l * 3072, nullptr, nullptr, big, 16384, 3072, 768, 12);
    gemm256<1><<<3 * 64, 512, 0, stream>>>(big, w2T + (long)l * D * F,
        b2 + l * 768, h, h, nullptr, 16384, 768, 3072, 3);
  }
}